// Round 1
// baseline (501.944 us; speedup 1.0000x reference)
//
#include <hip/hip_runtime.h>
#include <cstdint>
#include <cstddef>

#define SEQ 256
#define WDIM 256
#define CDIM 512
#define NHEAD 8
#define HD 64
#define NTOK (SEQ*WDIM)

typedef __attribute__((ext_vector_type(8))) short bf16x8;
typedef __attribute__((ext_vector_type(4))) float f32x4;
typedef __attribute__((ext_vector_type(8))) unsigned short u16x8;

static __device__ __forceinline__ unsigned short f2bf(float f) {
  union { float f; unsigned u; } v; v.f = f;
  return (unsigned short)((v.u + 0x7FFFu + ((v.u >> 16) & 1u)) >> 16);
}

// ---------------- kernel 0: fp32 -> bf16 conversion ----------------
__global__ void k_convert(const float* __restrict__ x,
                          const float* __restrict__ wqkv,
                          const float* __restrict__ wproj,
                          unsigned short* __restrict__ xb,
                          unsigned short* __restrict__ wqb,
                          unsigned short* __restrict__ wpb) {
  const int NX = NTOK*CDIM/4, NQ = 3*CDIM*CDIM/4, NP = CDIM*CDIM/4;
  const int total = NX + NQ + NP;
  for (int i = blockIdx.x*blockDim.x + threadIdx.x; i < total; i += gridDim.x*blockDim.x) {
    const float4* s; unsigned short* d; int j;
    if (i < NX)           { s = (const float4*)x;     d = xb;  j = i; }
    else if (i < NX+NQ)   { s = (const float4*)wqkv;  d = wqb; j = i-NX; }
    else                  { s = (const float4*)wproj; d = wpb; j = i-NX-NQ; }
    float4 f = s[j];
    ushort4 o;
    o.x = f2bf(f.x); o.y = f2bf(f.y); o.z = f2bf(f.z); o.w = f2bf(f.w);
    ((ushort4*)d)[j] = o;
  }
}

// ---------------- kernel 0b: RoPE cos/sin table [256][32] ----------------
__global__ void k_rope(float2* __restrict__ tab) {
  int i = blockIdx.x*blockDim.x + threadIdx.x;
  if (i >= SEQ*32) return;
  int h = i >> 5, j = i & 31;
  float freq = expf(-12.0f + 12.0f*(float)j/31.0f);
  float ang = ((float)h/255.0f) * freq * 256.0f;
  tab[i] = make_float2(cosf(ang), sinf(ang));
}

// ---------------- shared 128x128 GEMM core (K=512, both operands K-contig bf16) ----------------
__device__ __forceinline__ void gemm128(const unsigned short* __restrict__ A,
                                        const unsigned short* __restrict__ B,
                                        int rowA0, int rowB0,
                                        unsigned short* At, unsigned short* Bt,
                                        f32x4 (&acc)[4][4]) {
  const int tid = threadIdx.x;
  const int lane = tid & 63, wid = tid >> 6;
  const int wr = wid >> 1, wc = wid & 1;
  const int li = lane & 15, lg = lane >> 4;
  for (int kt = 0; kt < 8; ++kt) {
    #pragma unroll
    for (int c = 0; c < 4; ++c) {
      int chunk = wid*4 + c;                 // 0..15
      int o = chunk*1024 + lane*16;          // byte offset in 16KB tile
      int row = o >> 7;                      // /128 B per row
      int kbyte = o & 127;
      __builtin_amdgcn_global_load_lds(
        (const __attribute__((address_space(1))) unsigned int*)((const char*)A + (size_t)(rowA0+row)*1024 + kt*128 + kbyte),
        (__attribute__((address_space(3))) unsigned int*)((char*)At + o), 16, 0, 0);
      __builtin_amdgcn_global_load_lds(
        (const __attribute__((address_space(1))) unsigned int*)((const char*)B + (size_t)(rowB0+row)*1024 + kt*128 + kbyte),
        (__attribute__((address_space(3))) unsigned int*)((char*)Bt + o), 16, 0, 0);
    }
    __syncthreads();
    #pragma unroll
    for (int kk = 0; kk < 2; ++kk) {
      bf16x8 af[4], bfr[4];
      #pragma unroll
      for (int m = 0; m < 4; ++m)
        af[m] = *(const bf16x8*)&At[(wr*64 + m*16 + li)*64 + kk*32 + lg*8];
      #pragma unroll
      for (int n = 0; n < 4; ++n)
        bfr[n] = *(const bf16x8*)&Bt[(wc*64 + n*16 + li)*64 + kk*32 + lg*8];
      #pragma unroll
      for (int m = 0; m < 4; ++m)
        #pragma unroll
        for (int n = 0; n < 4; ++n)
          acc[m][n] = __builtin_amdgcn_mfma_f32_16x16x32_bf16(af[m], bfr[n], acc[m][n], 0, 0, 0);
    }
    __syncthreads();
  }
}

// ---------------- kernel 1: QKV GEMM + RMSNorm + RoPE + scatter ----------------
__launch_bounds__(256)
__global__ void k_qkv(const unsigned short* __restrict__ A,    // x bf16 [65536][512], t = h*256+w
                      const unsigned short* __restrict__ B,    // w_qkv bf16 [1536][512]
                      const float* __restrict__ qnw, const float* __restrict__ knw,
                      const float2* __restrict__ rope,         // [256][32]
                      unsigned short* __restrict__ Qw,
                      unsigned short* __restrict__ Kw,
                      unsigned short* __restrict__ Vw) {
  __shared__ __align__(16) unsigned short At[128*64];
  __shared__ __align__(16) unsigned short Bt[128*64];
  int bid = blockIdx.x;
  int bn = bid % 12, bm = bid / 12;        // bn fastest: consecutive blocks share A tile
  f32x4 acc[4][4] = {};
  gemm128(A, B, bm*128, bn*128, At, Bt, acc);

  const int lane = threadIdx.x & 63, wid = threadIdx.x >> 6;
  const int wr = wid >> 1, wc = wid & 1;
  const int li = lane & 15, lg = lane >> 4;
  int d0 = bn*128 + wc*64;                 // wave's absolute output-col base (64-aligned => one head)
  int third = d0 >> 9;                     // 0=q 1=k 2=v
  int nhh = (d0 >> 6) & 7;
  int t0 = bm*128 + wr*64;
  int hpos = (bm*128) >> 8;                // constant over the 128-token tile

  if (third == 2) {
    #pragma unroll
    for (int m = 0; m < 4; ++m)
      #pragma unroll
      for (int n = 0; n < 4; ++n)
        #pragma unroll
        for (int r = 0; r < 4; ++r) {
          int t = t0 + m*16 + lg*4 + r;
          int wI = t & 255;
          int e = n*16 + li;
          Vw[((size_t)(wI*8 + nhh)*256 + hpos)*64 + e] = f2bf(acc[m][n][r]);
        }
  } else {
    const float* nw = (third == 0) ? qnw : knw;
    unsigned short* dst = (third == 0) ? Qw : Kw;
    const float qsc = (third == 0) ? 0.125f : 1.0f;   // fold hd^-0.5 into q
    float nwv[4]; float2 cs[4];
    #pragma unroll
    for (int n = 0; n < 4; ++n) {
      int e = n*16 + li;
      nwv[n] = nw[e];
      cs[n] = rope[hpos*32 + (e >> 1)];
    }
    bool odd = (li & 1) != 0;
    #pragma unroll
    for (int m = 0; m < 4; ++m) {
      float rsg[4];
      #pragma unroll
      for (int r = 0; r < 4; ++r) {
        float p = 0.f;
        #pragma unroll
        for (int n = 0; n < 4; ++n) p += acc[m][n][r]*acc[m][n][r];
        #pragma unroll
        for (int d = 1; d < 16; d <<= 1) p += __shfl_xor(p, d, 64);   // 64-wide head reduce
        rsg[r] = rsqrtf(p*(1.0f/64.0f) + 1e-6f);
      }
      #pragma unroll
      for (int n = 0; n < 4; ++n)
        #pragma unroll
        for (int r = 0; r < 4; ++r) {
          float v = acc[m][n][r] * rsg[r] * nwv[n];
          float pr = __shfl_xor(v, 1, 64);            // rope pair partner
          float res = odd ? (pr*cs[n].y + v*cs[n].x) : (v*cs[n].x - pr*cs[n].y);
          res *= qsc;
          int t = t0 + m*16 + lg*4 + r;
          int wI = t & 255;
          int e = n*16 + li;
          dst[((size_t)(wI*8 + nhh)*256 + hpos)*64 + e] = f2bf(res);
        }
    }
  }
}

// ---------------- kernel 1t: V [h][e] -> VT [e][h] per (w,head) ----------------
__global__ void k_vt(const unsigned short* __restrict__ V, unsigned short* __restrict__ VT) {
  int b = blockIdx.x;                      // (w*8+n), 2048
  const unsigned short* src = V + (size_t)b*SEQ*HD;
  unsigned short* dst = VT + (size_t)b*SEQ*HD;
  int l = threadIdx.x & 63, wid = threadIdx.x >> 6;
  int h0 = (l & 31) * 8;
  int ebase = wid*2 + (l >> 5);
  #pragma unroll
  for (int eo = 0; eo < 8; ++eo) {
    int e = eo*8 + ebase;
    u16x8 v;
    #pragma unroll
    for (int i = 0; i < 8; ++i) v[i] = src[(h0+i)*64 + e];   // L1-absorbed gathers
    *(u16x8*)&dst[e*256 + h0] = v;                           // coalesced 16B stores
  }
}

// ---------------- kernel 2: attention per (w, head) ----------------
__launch_bounds__(256, 2)
__global__ void k_attn(const unsigned short* __restrict__ Q,
                       const unsigned short* __restrict__ K,
                       const unsigned short* __restrict__ VT,
                       unsigned short* __restrict__ O) {
  __shared__ __align__(16) unsigned short P_lds[4][64*64];   // 8KB/wave, XOR-swizzled [q][key]
  int b = blockIdx.x;
  const unsigned short* Qb = Q  + (size_t)b*SEQ*HD;
  const unsigned short* Kb = K  + (size_t)b*SEQ*HD;
  const unsigned short* Vb = VT + (size_t)b*SEQ*HD;          // [e][h]
  const int lane = threadIdx.x & 63, wid = threadIdx.x >> 6;
  const int li = lane & 15, lg = lane >> 4;
  const int q0 = wid*64;
  char* Pw = (char*)&P_lds[wid][0];

  bf16x8 qf[4][2];                                           // Q resident in regs
  #pragma unroll
  for (int n = 0; n < 4; ++n)
    #pragma unroll
    for (int kk = 0; kk < 2; ++kk)
      qf[n][kk] = *(const bf16x8*)(Qb + (q0 + n*16 + li)*64 + kk*32 + lg*8);

  f32x4 oa[4][4] = {};
  float mrun[4], lrun[4];
  #pragma unroll
  for (int n = 0; n < 4; ++n) { mrun[n] = -1e30f; lrun[n] = 0.0f; }

  #pragma unroll 1
  for (int kb = 0; kb < 4; ++kb) {
    int key0 = kb*64;
    // S^T[key][q] = K @ Q^T  (reg-quad = 4 consecutive keys -> b64 pack into P[q][key])
    f32x4 s[4][4] = {};
    #pragma unroll
    for (int kk = 0; kk < 2; ++kk) {
      bf16x8 kf[4];
      #pragma unroll
      for (int m = 0; m < 4; ++m)
        kf[m] = *(const bf16x8*)(Kb + (key0 + m*16 + li)*64 + kk*32 + lg*8);
      #pragma unroll
      for (int m = 0; m < 4; ++m)
        #pragma unroll
        for (int n = 0; n < 4; ++n)
          s[m][n] = __builtin_amdgcn_mfma_f32_16x16x32_bf16(kf[m], qf[n][kk], s[m][n], 0, 0, 0);
    }
    // online softmax: per lane state for q = n*16+li (replicated across lg, kept consistent)
    float mx[4], al[4];
    #pragma unroll
    for (int n = 0; n < 4; ++n) {
      float v = -1e30f;
      #pragma unroll
      for (int m = 0; m < 4; ++m)
        #pragma unroll
        for (int r = 0; r < 4; ++r) v = fmaxf(v, s[m][n][r]);
      v = fmaxf(v, __shfl_xor(v, 16, 64));
      v = fmaxf(v, __shfl_xor(v, 32, 64));
      float mn = fmaxf(mrun[n], v);
      al[n] = __expf(mrun[n] - mn);
      mrun[n] = mn;
      mx[n] = mn;
    }
    float rs[4] = {0.f,0.f,0.f,0.f};
    #pragma unroll
    for (int m = 0; m < 4; ++m)
      #pragma unroll
      for (int n = 0; n < 4; ++n) {
        f32x4 sv = s[m][n];
        #pragma unroll
        for (int r = 0; r < 4; ++r) {
          float p = __expf(sv[r] - mx[n]);
          sv[r] = p; rs[n] += p;
        }
        unsigned lo = (unsigned)f2bf(sv[0]) | ((unsigned)f2bf(sv[1]) << 16);
        unsigned hi = (unsigned)f2bf(sv[2]) | ((unsigned)f2bf(sv[3]) << 16);
        uint2 pk; pk.x = lo; pk.y = hi;
        int q = n*16 + li;
        int off = (q*128 + (m*16 + lg*4)*2) ^ ((li & 7) << 4);   // XOR swizzle (T2)
        *(uint2*)(Pw + off) = pk;
      }
    #pragma unroll
    for (int n = 0; n < 4; ++n) {
      rs[n] += __shfl_xor(rs[n], 16, 64);
      rs[n] += __shfl_xor(rs[n], 32, 64);
      lrun[n] = lrun[n]*al[n] + rs[n];
    }
    // rescale O: broadcast alpha[q] from softmax layout to O layout via bpermute
    #pragma unroll
    for (int mp = 0; mp < 4; ++mp)
      #pragma unroll
      for (int r = 0; r < 4; ++r) {
        float a = __shfl(al[mp], lg*4 + r, 64);
        #pragma unroll
        for (int np = 0; np < 4; ++np) oa[mp][np][r] *= a;
      }
    // PV: O[q][e] += P[q][key] @ V[key][e]  (A=P from swizzled LDS, B=VT from global)
    #pragma unroll
    for (int kk = 0; kk < 2; ++kk) {
      bf16x8 pf[4], vf[4];
      #pragma unroll
      for (int mp = 0; mp < 4; ++mp) {
        int q = mp*16 + li;
        int off = (q*128 + (kk*32 + lg*8)*2) ^ ((li & 7) << 4);
        pf[mp] = *(const bf16x8*)(Pw + off);
      }
      #pragma unroll
      for (int np = 0; np < 4; ++np)
        vf[np] = *(const bf16x8*)(Vb + (np*16 + li)*256 + key0 + kk*32 + lg*8);
      #pragma unroll
      for (int mp = 0; mp < 4; ++mp)
        #pragma unroll
        for (int np = 0; np < 4; ++np)
          oa[mp][np] = __builtin_amdgcn_mfma_f32_16x16x32_bf16(pf[mp], vf[np], oa[mp][np], 0, 0, 0);
    }
  }
  // finalize: divide by l, store O_ws rows t = h*256+w, cols head*64+e
  int wseq = b >> 3, whead = b & 7;
  #pragma unroll
  for (int mp = 0; mp < 4; ++mp)
    #pragma unroll
    for (int r = 0; r < 4; ++r) {
      float linv = 1.0f / __shfl(lrun[mp], lg*4 + r, 64);
      #pragma unroll
      for (int np = 0; np < 4; ++np) {
        int q = q0 + mp*16 + lg*4 + r;
        int e = np*16 + li;
        O[((size_t)q*WDIM + wseq)*CDIM + whead*HD + e] = f2bf(oa[mp][np][r] * linv);
      }
    }
}

// ---------------- kernel 3: out-proj GEMM + bias, fp32 out ----------------
__launch_bounds__(256)
__global__ void k_proj(const unsigned short* __restrict__ A,   // O bf16 [65536][512]
                       const unsigned short* __restrict__ B,   // w_proj bf16 [512][512]
                       const float* __restrict__ bias,
                       float* __restrict__ out) {
  __shared__ __align__(16) unsigned short At[128*64];
  __shared__ __align__(16) unsigned short Bt[128*64];
  int bid = blockIdx.x;
  int bn = bid & 3, bm = bid >> 2;
  f32x4 acc[4][4] = {};
  gemm128(A, B, bm*128, bn*128, At, Bt, acc);

  const int lane = threadIdx.x & 63, wid = threadIdx.x >> 6;
  const int wr = wid >> 1, wc = wid & 1;
  const int li = lane & 15, lg = lane >> 4;
  int d0 = bn*128 + wc*64;
  int t0 = bm*128 + wr*64;
  float bi[4];
  #pragma unroll
  for (int n = 0; n < 4; ++n) bi[n] = bias[d0 + n*16 + li];
  #pragma unroll
  for (int m = 0; m < 4; ++m)
    #pragma unroll
    for (int n = 0; n < 4; ++n)
      #pragma unroll
      for (int r = 0; r < 4; ++r)
        out[(size_t)(t0 + m*16 + lg*4 + r)*CDIM + d0 + n*16 + li] = acc[m][n][r] + bi[n];
}

extern "C" void kernel_launch(void* const* d_in, const int* in_sizes, int n_in,
                              void* d_out, int out_size, void* d_ws, size_t ws_size,
                              hipStream_t stream) {
  (void)in_sizes; (void)n_in; (void)out_size; (void)ws_size;
  const float* x     = (const float*)d_in[0];
  const float* wqkv  = (const float*)d_in[1];
  const float* qnw   = (const float*)d_in[2];
  const float* knw   = (const float*)d_in[3];
  const float* wproj = (const float*)d_in[4];
  const float* bproj = (const float*)d_in[5];
  float* out = (float*)d_out;
  char* ws = (char*)d_ws;

  const size_t SZ_X = (size_t)NTOK*CDIM*2;                     // 64 MiB of bf16
  unsigned short* xb  = (unsigned short*)(ws);
  unsigned short* wqb = (unsigned short*)(ws + SZ_X);
  unsigned short* wpb = (unsigned short*)(ws + SZ_X + 1572864);
  float2*         rp  = (float2*)       (ws + SZ_X + 1572864 + 524288);
  unsigned short* Qw  = (unsigned short*)(ws + SZ_X + 1572864 + 524288 + 65536);
  unsigned short* Kw  = (unsigned short*)((char*)Qw + SZ_X);
  unsigned short* Vw  = (unsigned short*)((char*)Kw + SZ_X);
  unsigned short* VTw = (unsigned short*)((char*)Vw + SZ_X);
  unsigned short* Ow  = xb;   // x is dead after k_qkv; reuse its slot for attention output

  k_convert<<<dim3(2048), dim3(256), 0, stream>>>(x, wqkv, wproj, xb, wqb, wpb);
  k_rope   <<<dim3(32),   dim3(256), 0, stream>>>(rp);
  k_qkv    <<<dim3(6144), dim3(256), 0, stream>>>(xb, wqb, qnw, knw, rp, Qw, Kw, Vw);
  k_vt     <<<dim3(2048), dim3(256), 0, stream>>>(Vw, VTw);
  k_attn   <<<dim3(2048), dim3(256), 0, stream>>>(Qw, Kw, VTw, Ow);
  k_proj   <<<dim3(2048), dim3(256), 0, stream>>>(Ow, wpb, bproj, out);
}

// Round 2
// 494.090 us; speedup vs baseline: 1.0159x; 1.0159x over previous
//
#include <hip/hip_runtime.h>
#include <cstdint>
#include <cstddef>

#define SEQ 256
#define WDIM 256
#define CDIM 512
#define NHEAD 8
#define HD 64
#define NTOK (SEQ*WDIM)

typedef __attribute__((ext_vector_type(8))) short bf16x8;
typedef __attribute__((ext_vector_type(4))) float f32x4;
typedef __attribute__((ext_vector_type(8))) unsigned short u16x8;

static __device__ __forceinline__ unsigned short f2bf(float f) {
  union { float f; unsigned u; } v; v.f = f;
  return (unsigned short)((v.u + 0x7FFFu + ((v.u >> 16) & 1u)) >> 16);
}

// ---------------- kernel 0: fp32 -> bf16 conversion ----------------
__global__ void k_convert(const float* __restrict__ x,
                          const float* __restrict__ wqkv,
                          const float* __restrict__ wproj,
                          unsigned short* __restrict__ xb,
                          unsigned short* __restrict__ wqb,
                          unsigned short* __restrict__ wpb) {
  const int NX = NTOK*CDIM/4, NQ = 3*CDIM*CDIM/4, NP = CDIM*CDIM/4;
  const int total = NX + NQ + NP;
  for (int i = blockIdx.x*blockDim.x + threadIdx.x; i < total; i += gridDim.x*blockDim.x) {
    const float4* s; unsigned short* d; int j;
    if (i < NX)           { s = (const float4*)x;     d = xb;  j = i; }
    else if (i < NX+NQ)   { s = (const float4*)wqkv;  d = wqb; j = i-NX; }
    else                  { s = (const float4*)wproj; d = wpb; j = i-NX-NQ; }
    float4 f = s[j];
    ushort4 o;
    o.x = f2bf(f.x); o.y = f2bf(f.y); o.z = f2bf(f.z); o.w = f2bf(f.w);
    ((ushort4*)d)[j] = o;
  }
}

// ---------------- kernel 0b: RoPE cos/sin table [256][32] ----------------
__global__ void k_rope(float2* __restrict__ tab) {
  int i = blockIdx.x*blockDim.x + threadIdx.x;
  if (i >= SEQ*32) return;
  int h = i >> 5, j = i & 31;
  float freq = expf(-12.0f + 12.0f*(float)j/31.0f);
  float ang = ((float)h/255.0f) * freq * 256.0f;
  tab[i] = make_float2(cosf(ang), sinf(ang));
}

// ---------------- shared 128x128 GEMM core, 2-phase double-buffered ----------------
// T3-lite: STAGE(next) issued BEFORE ds_read+MFMA of current; one __syncthreads per
// K-step (its implicit vmcnt(0) drains loads that had the whole compute phase in flight).
__device__ __forceinline__ void gemm128_db(const unsigned short* __restrict__ A,
                                           const unsigned short* __restrict__ B,
                                           int rowA0, int rowB0,
                                           unsigned short* At, unsigned short* Bt, // each [2][128*64]
                                           f32x4 (&acc)[4][4]) {
  const int tid = threadIdx.x;
  const int lane = tid & 63, wid = tid >> 6;
  const int wr = wid >> 1, wc = wid & 1;
  const int li = lane & 15, lg = lane >> 4;
  const int chunk_o = (wid*4)*1024 + lane*16;     // this thread's first 16B slot

#define STAGE(kt, p)                                                                          \
  {                                                                                           \
    _Pragma("unroll")                                                                         \
    for (int c = 0; c < 4; ++c) {                                                             \
      int o = chunk_o + c*1024;                                                               \
      int row = o >> 7, kbyte = o & 127;                                                      \
      __builtin_amdgcn_global_load_lds(                                                       \
        (const __attribute__((address_space(1))) unsigned int*)((const char*)A + (size_t)(rowA0+row)*1024 + (kt)*128 + kbyte), \
        (__attribute__((address_space(3))) unsigned int*)((char*)At + (p)*16384 + o), 16, 0, 0); \
      __builtin_amdgcn_global_load_lds(                                                       \
        (const __attribute__((address_space(1))) unsigned int*)((const char*)B + (size_t)(rowB0+row)*1024 + (kt)*128 + kbyte), \
        (__attribute__((address_space(3))) unsigned int*)((char*)Bt + (p)*16384 + o), 16, 0, 0); \
    }                                                                                         \
  }

  STAGE(0, 0);
  __syncthreads();
  #pragma unroll 1
  for (int kt = 0; kt < 8; ++kt) {
    int cur = kt & 1;
    if (kt < 7) STAGE(kt+1, cur^1);               // prefetch overlaps with compute below
    const unsigned short* Ab = At + cur*8192;
    const unsigned short* Bb = Bt + cur*8192;
    bf16x8 af[2][4], bfr[2][4];
    #pragma unroll
    for (int kk = 0; kk < 2; ++kk) {
      #pragma unroll
      for (int m = 0; m < 4; ++m)
        af[kk][m] = *(const bf16x8*)&Ab[(wr*64 + m*16 + li)*64 + kk*32 + lg*8];
      #pragma unroll
      for (int n = 0; n < 4; ++n)
        bfr[kk][n] = *(const bf16x8*)&Bb[(wc*64 + n*16 + li)*64 + kk*32 + lg*8];
    }
    #pragma unroll
    for (int kk = 0; kk < 2; ++kk)
      #pragma unroll
      for (int m = 0; m < 4; ++m)
        #pragma unroll
        for (int n = 0; n < 4; ++n)
          acc[m][n] = __builtin_amdgcn_mfma_f32_16x16x32_bf16(af[kk][m], bfr[kk][n], acc[m][n], 0, 0, 0);
    __syncthreads();                               // vmcnt(0)+lgkmcnt(0)+barrier: next tile ready
  }
#undef STAGE
}

// ---------------- kernel 1: QKV GEMM + RMSNorm + RoPE + scatter ----------------
__launch_bounds__(256)
__global__ void k_qkv(const unsigned short* __restrict__ A,    // x bf16 [65536][512], t = h*256+w
                      const unsigned short* __restrict__ B,    // w_qkv bf16 [1536][512]
                      const float* __restrict__ qnw, const float* __restrict__ knw,
                      const float2* __restrict__ rope,         // [256][32]
                      unsigned short* __restrict__ Qw,
                      unsigned short* __restrict__ Kw,
                      unsigned short* __restrict__ Vw) {
  __shared__ __align__(16) unsigned short At[2*128*64];
  __shared__ __align__(16) unsigned short Bt[2*128*64];
  // T1: XCD-chunked bijective swizzle (6144 = 8 XCD * 768; 768 = 64 complete bn-groups)
  int wg = (blockIdx.x & 7)*768 + (blockIdx.x >> 3);
  int bn = wg % 12, bm = wg / 12;          // bn fastest: consecutive wg share A tile, same XCD
  f32x4 acc[4][4] = {};
  gemm128_db(A, B, bm*128, bn*128, At, Bt, acc);

  const int lane = threadIdx.x & 63, wid = threadIdx.x >> 6;
  const int wr = wid >> 1, wc = wid & 1;
  const int li = lane & 15, lg = lane >> 4;
  int d0 = bn*128 + wc*64;                 // wave's absolute output-col base (64-aligned => one head)
  int third = d0 >> 9;                     // 0=q 1=k 2=v
  int nhh = (d0 >> 6) & 7;
  int t0 = bm*128 + wr*64;
  int hpos = (bm*128) >> 8;                // constant over the 128-token tile

  if (third == 2) {
    #pragma unroll
    for (int m = 0; m < 4; ++m)
      #pragma unroll
      for (int n = 0; n < 4; ++n)
        #pragma unroll
        for (int r = 0; r < 4; ++r) {
          int t = t0 + m*16 + lg*4 + r;
          int wI = t & 255;
          int e = n*16 + li;
          Vw[((size_t)(wI*8 + nhh)*256 + hpos)*64 + e] = f2bf(acc[m][n][r]);
        }
  } else {
    const float* nw = (third == 0) ? qnw : knw;
    unsigned short* dst = (third == 0) ? Qw : Kw;
    const float qsc = (third == 0) ? 0.125f : 1.0f;   // fold hd^-0.5 into q
    float nwv[4]; float2 cs[4];
    #pragma unroll
    for (int n = 0; n < 4; ++n) {
      int e = n*16 + li;
      nwv[n] = nw[e];
      cs[n] = rope[hpos*32 + (e >> 1)];
    }
    bool odd = (li & 1) != 0;
    #pragma unroll
    for (int m = 0; m < 4; ++m) {
      float rsg[4];
      #pragma unroll
      for (int r = 0; r < 4; ++r) {
        float p = 0.f;
        #pragma unroll
        for (int n = 0; n < 4; ++n) p += acc[m][n][r]*acc[m][n][r];
        #pragma unroll
        for (int d = 1; d < 16; d <<= 1) p += __shfl_xor(p, d, 64);   // head-dim reduce (li groups)
        rsg[r] = rsqrtf(p*(1.0f/64.0f) + 1e-6f);
      }
      #pragma unroll
      for (int n = 0; n < 4; ++n)
        #pragma unroll
        for (int r = 0; r < 4; ++r) {
          float v = acc[m][n][r] * rsg[r] * nwv[n];
          float pr = __shfl_xor(v, 1, 64);            // rope pair partner
          float res = odd ? (pr*cs[n].y + v*cs[n].x) : (v*cs[n].x - pr*cs[n].y);
          res *= qsc;
          int t = t0 + m*16 + lg*4 + r;
          int wI = t & 255;
          int e = n*16 + li;
          dst[((size_t)(wI*8 + nhh)*256 + hpos)*64 + e] = f2bf(res);
        }
    }
  }
}

// ---------------- kernel 1t: V [h][e] -> VT [e][h] per (w,head) ----------------
__global__ void k_vt(const unsigned short* __restrict__ V, unsigned short* __restrict__ VT) {
  int b = blockIdx.x;                      // (w*8+n), 2048
  const unsigned short* src = V + (size_t)b*SEQ*HD;
  unsigned short* dst = VT + (size_t)b*SEQ*HD;
  int l = threadIdx.x & 63, wid = threadIdx.x >> 6;
  int h0 = (l & 31) * 8;
  int ebase = wid*2 + (l >> 5);
  #pragma unroll
  for (int eo = 0; eo < 8; ++eo) {
    int e = eo*8 + ebase;
    u16x8 v;
    #pragma unroll
    for (int i = 0; i < 8; ++i) v[i] = src[(h0+i)*64 + e];   // L1-absorbed gathers
    *(u16x8*)&dst[e*256 + h0] = v;                           // coalesced 16B stores
  }
}

// ---------------- kernel 2: attention per (w, head) ----------------
__launch_bounds__(256, 2)
__global__ void k_attn(const unsigned short* __restrict__ Q,
                       const unsigned short* __restrict__ K,
                       const unsigned short* __restrict__ VT,
                       unsigned short* __restrict__ O) {
  __shared__ __align__(16) unsigned short P_lds[4][64*64];   // 8KB/wave, XOR-swizzled [q][key]
  int b = blockIdx.x;
  const unsigned short* Qb = Q  + (size_t)b*SEQ*HD;
  const unsigned short* Kb = K  + (size_t)b*SEQ*HD;
  const unsigned short* Vb = VT + (size_t)b*SEQ*HD;          // [e][h]
  const int lane = threadIdx.x & 63, wid = threadIdx.x >> 6;
  const int li = lane & 15, lg = lane >> 4;
  const int q0 = wid*64;
  char* Pw = (char*)&P_lds[wid][0];

  bf16x8 qf[4][2];                                           // Q resident in regs
  #pragma unroll
  for (int n = 0; n < 4; ++n)
    #pragma unroll
    for (int kk = 0; kk < 2; ++kk)
      qf[n][kk] = *(const bf16x8*)(Qb + (q0 + n*16 + li)*64 + kk*32 + lg*8);

  f32x4 oa[4][4] = {};
  float mrun[4], lrun[4];
  #pragma unroll
  for (int n = 0; n < 4; ++n) { mrun[n] = -1e30f; lrun[n] = 0.0f; }

  #pragma unroll 1
  for (int kb = 0; kb < 4; ++kb) {
    int key0 = kb*64;
    // S^T[key][q] = K @ Q^T  (reg-quad = 4 consecutive keys -> b64 pack into P[q][key])
    f32x4 s[4][4] = {};
    #pragma unroll
    for (int kk = 0; kk < 2; ++kk) {
      bf16x8 kf[4];
      #pragma unroll
      for (int m = 0; m < 4; ++m)
        kf[m] = *(const bf16x8*)(Kb + (key0 + m*16 + li)*64 + kk*32 + lg*8);
      __builtin_amdgcn_s_setprio(1);
      #pragma unroll
      for (int m = 0; m < 4; ++m)
        #pragma unroll
        for (int n = 0; n < 4; ++n)
          s[m][n] = __builtin_amdgcn_mfma_f32_16x16x32_bf16(kf[m], qf[n][kk], s[m][n], 0, 0, 0);
      __builtin_amdgcn_s_setprio(0);
    }
    // online softmax: per lane state for q = n*16+li (replicated across lg, kept consistent)
    float mx[4], al[4];
    #pragma unroll
    for (int n = 0; n < 4; ++n) {
      float v = -1e30f;
      #pragma unroll
      for (int m = 0; m < 4; ++m)
        #pragma unroll
        for (int r = 0; r < 4; ++r) v = fmaxf(v, s[m][n][r]);
      v = fmaxf(v, __shfl_xor(v, 16, 64));
      v = fmaxf(v, __shfl_xor(v, 32, 64));
      float mn = fmaxf(mrun[n], v);
      al[n] = __expf(mrun[n] - mn);
      mrun[n] = mn;
      mx[n] = mn;
    }
    float rs[4] = {0.f,0.f,0.f,0.f};
    #pragma unroll
    for (int m = 0; m < 4; ++m)
      #pragma unroll
      for (int n = 0; n < 4; ++n) {
        f32x4 sv = s[m][n];
        #pragma unroll
        for (int r = 0; r < 4; ++r) {
          float p = __expf(sv[r] - mx[n]);
          sv[r] = p; rs[n] += p;
        }
        unsigned lo = (unsigned)f2bf(sv[0]) | ((unsigned)f2bf(sv[1]) << 16);
        unsigned hi = (unsigned)f2bf(sv[2]) | ((unsigned)f2bf(sv[3]) << 16);
        uint2 pk; pk.x = lo; pk.y = hi;
        int q = n*16 + li;
        int off = (q*128 + (m*16 + lg*4)*2) ^ ((li & 7) << 4);   // XOR swizzle (T2)
        *(uint2*)(Pw + off) = pk;
      }
    #pragma unroll
    for (int n = 0; n < 4; ++n) {
      rs[n] += __shfl_xor(rs[n], 16, 64);
      rs[n] += __shfl_xor(rs[n], 32, 64);
      lrun[n] = lrun[n]*al[n] + rs[n];
    }
    // rescale O: broadcast alpha[q] from softmax layout to O layout
    #pragma unroll
    for (int mp = 0; mp < 4; ++mp)
      #pragma unroll
      for (int r = 0; r < 4; ++r) {
        float a = __shfl(al[mp], lg*4 + r, 64);
        #pragma unroll
        for (int np = 0; np < 4; ++np) oa[mp][np][r] *= a;
      }
    // PV: O[q][e] += P[q][key] @ V[key][e]  (A=P from swizzled LDS, B=VT from global)
    #pragma unroll
    for (int kk = 0; kk < 2; ++kk) {
      bf16x8 pf[4], vf[4];
      #pragma unroll
      for (int mp = 0; mp < 4; ++mp) {
        int q = mp*16 + li;
        int off = (q*128 + (kk*32 + lg*8)*2) ^ ((li & 7) << 4);
        pf[mp] = *(const bf16x8*)(Pw + off);
      }
      #pragma unroll
      for (int np = 0; np < 4; ++np)
        vf[np] = *(const bf16x8*)(Vb + (np*16 + li)*256 + key0 + kk*32 + lg*8);
      __builtin_amdgcn_s_setprio(1);
      #pragma unroll
      for (int mp = 0; mp < 4; ++mp)
        #pragma unroll
        for (int np = 0; np < 4; ++np)
          oa[mp][np] = __builtin_amdgcn_mfma_f32_16x16x32_bf16(pf[mp], vf[np], oa[mp][np], 0, 0, 0);
      __builtin_amdgcn_s_setprio(0);
    }
  }
  // finalize: divide by l, store O_ws rows t = h*256+w, cols head*64+e
  int wseq = b >> 3, whead = b & 7;
  #pragma unroll
  for (int mp = 0; mp < 4; ++mp)
    #pragma unroll
    for (int r = 0; r < 4; ++r) {
      float linv = 1.0f / __shfl(lrun[mp], lg*4 + r, 64);
      #pragma unroll
      for (int np = 0; np < 4; ++np) {
        int q = q0 + mp*16 + lg*4 + r;
        int e = np*16 + li;
        O[((size_t)q*WDIM + wseq)*CDIM + whead*HD + e] = f2bf(oa[mp][np][r] * linv);
      }
    }
}

// ---------------- kernel 3: out-proj GEMM + bias, fp32 out ----------------
__launch_bounds__(256)
__global__ void k_proj(const unsigned short* __restrict__ A,   // O bf16 [65536][512]
                       const unsigned short* __restrict__ B,   // w_proj bf16 [512][512]
                       const float* __restrict__ bias,
                       float* __restrict__ out) {
  __shared__ __align__(16) unsigned short At[2*128*64];
  __shared__ __align__(16) unsigned short Bt[2*128*64];
  // T1: 2048 = 8 XCD * 256; 256 = 64 complete bn-groups of 4
  int wg = (blockIdx.x & 7)*256 + (blockIdx.x >> 3);
  int bn = wg & 3, bm = wg >> 2;
  f32x4 acc[4][4] = {};
  gemm128_db(A, B, bm*128, bn*128, At, Bt, acc);

  const int lane = threadIdx.x & 63, wid = threadIdx.x >> 6;
  const int wr = wid >> 1, wc = wid & 1;
  const int li = lane & 15, lg = lane >> 4;
  int d0 = bn*128 + wc*64;
  int t0 = bm*128 + wr*64;
  float bi[4];
  #pragma unroll
  for (int n = 0; n < 4; ++n) bi[n] = bias[d0 + n*16 + li];
  #pragma unroll
  for (int m = 0; m < 4; ++m)
    #pragma unroll
    for (int n = 0; n < 4; ++n)
      #pragma unroll
      for (int r = 0; r < 4; ++r)
        out[(size_t)(t0 + m*16 + lg*4 + r)*CDIM + d0 + n*16 + li] = acc[m][n][r] + bi[n];
}

extern "C" void kernel_launch(void* const* d_in, const int* in_sizes, int n_in,
                              void* d_out, int out_size, void* d_ws, size_t ws_size,
                              hipStream_t stream) {
  (void)in_sizes; (void)n_in; (void)out_size; (void)ws_size;
  const float* x     = (const float*)d_in[0];
  const float* wqkv  = (const float*)d_in[1];
  const float* qnw   = (const float*)d_in[2];
  const float* knw   = (const float*)d_in[3];
  const float* wproj = (const float*)d_in[4];
  const float* bproj = (const float*)d_in[5];
  float* out = (float*)d_out;
  char* ws = (char*)d_ws;

  const size_t SZ_X = (size_t)NTOK*CDIM*2;                     // 64 MiB of bf16
  unsigned short* xb  = (unsigned short*)(ws);
  unsigned short* wqb = (unsigned short*)(ws + SZ_X);
  unsigned short* wpb = (unsigned short*)(ws + SZ_X + 1572864);
  float2*         rp  = (float2*)       (ws + SZ_X + 1572864 + 524288);
  unsigned short* Qw  = (unsigned short*)(ws + SZ_X + 1572864 + 524288 + 65536);
  unsigned short* Kw  = (unsigned short*)((char*)Qw + SZ_X);
  unsigned short* Vw  = (unsigned short*)((char*)Kw + SZ_X);
  unsigned short* VTw = (unsigned short*)((char*)Vw + SZ_X);
  unsigned short* Ow  = xb;   // x is dead after k_qkv; reuse its slot for attention output

  k_convert<<<dim3(2048), dim3(256), 0, stream>>>(x, wqkv, wproj, xb, wqb, wpb);
  k_rope   <<<dim3(32),   dim3(256), 0, stream>>>(rp);
  k_qkv    <<<dim3(6144), dim3(256), 0, stream>>>(xb, wqb, qnw, knw, rp, Qw, Kw, Vw);
  k_vt     <<<dim3(2048), dim3(256), 0, stream>>>(Vw, VTw);
  k_attn   <<<dim3(2048), dim3(256), 0, stream>>>(Qw, Kw, VTw, Ow);
  k_proj   <<<dim3(2048), dim3(256), 0, stream>>>(Ow, wpb, bproj, out);
}

// Round 4
// 405.234 us; speedup vs baseline: 1.2387x; 1.2193x over previous
//
#include <hip/hip_runtime.h>
#include <cstdint>
#include <cstddef>

#define SEQ 256
#define WDIM 256
#define CDIM 512
#define NHEAD 8
#define HD 64
#define NTOK (SEQ*WDIM)
#define NT_TILES 8   // K=512 / BK=64

typedef __attribute__((ext_vector_type(8))) short bf16x8;
typedef __attribute__((ext_vector_type(4))) float f32x4;
typedef __attribute__((ext_vector_type(8))) unsigned short u16x8;

static __device__ __forceinline__ unsigned short f2bf(float f) {
  union { float f; unsigned u; } v; v.f = f;
  return (unsigned short)((v.u + 0x7FFFu + ((v.u >> 16) & 1u)) >> 16);
}

// ---------------- kernel 0: fp32 -> bf16 conversion ----------------
__global__ void k_convert(const float* __restrict__ x,
                          const float* __restrict__ wqkv,
                          const float* __restrict__ wproj,
                          unsigned short* __restrict__ xb,
                          unsigned short* __restrict__ wqb,
                          unsigned short* __restrict__ wpb) {
  const int NX = NTOK*CDIM/4, NQ = 3*CDIM*CDIM/4, NP = CDIM*CDIM/4;
  const int total = NX + NQ + NP;
  for (int i = blockIdx.x*blockDim.x + threadIdx.x; i < total; i += gridDim.x*blockDim.x) {
    const float4* s; unsigned short* d; int j;
    if (i < NX)           { s = (const float4*)x;     d = xb;  j = i; }
    else if (i < NX+NQ)   { s = (const float4*)wqkv;  d = wqb; j = i-NX; }
    else                  { s = (const float4*)wproj; d = wpb; j = i-NX-NQ; }
    float4 f = s[j];
    ushort4 o;
    o.x = f2bf(f.x); o.y = f2bf(f.y); o.z = f2bf(f.z); o.w = f2bf(f.w);
    ((ushort4*)d)[j] = o;
  }
}

// ---------------- kernel 0b: RoPE cos/sin table [256][32] ----------------
__global__ void k_rope(float2* __restrict__ tab) {
  int i = blockIdx.x*blockDim.x + threadIdx.x;
  if (i >= SEQ*32) return;
  int h = i >> 5, j = i & 31;
  float freq = expf(-12.0f + 12.0f*(float)j/31.0f);
  float ang = ((float)h/255.0f) * freq * 256.0f;
  tab[i] = make_float2(cosf(ang), sinf(ang));
}

// ============ 256x256 8-phase GEMM core (K=512, both operands K-contig bf16) ============
// LDS layout: L[buf][A=0/B=1][half][128 rows][8 granules], granule g stored at g^(row&7)
// (T2 both-sides involution: pre-swizzled global source + swizzled ds_read; gload_lds dest linear).
// Half-tile h (= tile*4 + {A0,A1,B0,B1}) staged one per phase, 6-phase lead.
// vmcnt ledger: end-of-tile-T wait must land ALL of tile T+1. Mid-loop in-flight =
// {T+1:A0,A1,B0,B1, T+2:A0,A1} = 12 instrs -> vmcnt(4). For T >= NT-2 the tile-T+2
// stages are skipped, so in-flight is only 8 -> vmcnt(4) would leave T+1's B in flight
// (the R3 bug). Use vmcnt(0) there.

#define STAGE_H(h_)                                                                        \
  {                                                                                        \
    const int t_ = (h_) >> 2, part_ = (h_) & 3;                                            \
    const int buf_ = t_ & 1, ab_ = part_ >> 1, hh_ = part_ & 1;                            \
    const unsigned short* src_ = ab_ ? B : A;                                              \
    const int row0_ = (ab_ ? rowB0 : rowA0) + hh_*128;                                     \
    _Pragma("unroll")                                                                      \
    for (int c_ = 0; c_ < 2; ++c_) {                                                       \
      int G_ = wid*128 + c_*64 + lane;                                                     \
      int r_ = G_ >> 3, g_ = G_ & 7;                                                       \
      int gsw_ = g_ ^ (r_ & 7);                                                            \
      __builtin_amdgcn_global_load_lds(                                                    \
        (const __attribute__((address_space(1))) unsigned int*)                            \
          ((const char*)src_ + (size_t)(row0_ + r_)*1024 + (size_t)t_*128 + gsw_*16),      \
        (__attribute__((address_space(3))) unsigned int*)                                  \
          ((char*)&L[buf_][ab_][hh_][0] + G_*16),                                          \
        16, 0, 0);                                                                         \
    }                                                                                      \
  }

#define LDA_(dst, m_, kk_)                                                                 \
  { int r_ = (m_)*16 + li;                                                                 \
    dst = *(const bf16x8*)((const char*)&L[buf][0][wr][0] + r_*128 + (((((kk_)*4)+lg) ^ (r_ & 7))<<4)); }
#define LDB_(dst, n_, kk_)                                                                 \
  { int r_ = (wc & 1)*64 + (n_)*16 + li;                                                   \
    dst = *(const bf16x8*)((const char*)&L[buf][1][wc>>1][0] + r_*128 + (((((kk_)*4)+lg) ^ (r_ & 7))<<4)); }

__device__ __forceinline__ void gemm256(const unsigned short* __restrict__ A,
                                        const unsigned short* __restrict__ B,
                                        int rowA0, int rowB0,
                                        unsigned short (&L)[2][2][2][128*64],
                                        f32x4 (&acc)[8][4]) {
  const int tid = threadIdx.x;
  const int lane = tid & 63, wid = tid >> 6;
  const int wr = wid >> 2, wc = wid & 3;
  const int li = lane & 15, lg = lane >> 4;

  #pragma unroll
  for (int h = 0; h < 6; ++h) STAGE_H(h);
  asm volatile("s_waitcnt vmcnt(4)" ::: "memory");
  __builtin_amdgcn_s_barrier();

  #pragma unroll 1
  for (int T = 0; T < NT_TILES; ++T) {
    const int buf = T & 1;
    bf16x8 aE[4], aL0[4], aL1[4], bb0[4], bb1[4];
    // ---- phase 0: read A[0..3][kk0], A[0..3][kk1], B[kk0]; MFMA quadrant (m0-3, kk0) ----
    #pragma unroll
    for (int m = 0; m < 4; ++m) { LDA_(aE[m], m, 0); LDA_(aL0[m], m, 1); }
    #pragma unroll
    for (int n = 0; n < 4; ++n) { LDB_(bb0[n], n, 0); }
    if (4*T+6 < 4*NT_TILES) STAGE_H(4*T+6);
    __builtin_amdgcn_s_barrier();
    asm volatile("s_waitcnt lgkmcnt(0)" ::: "memory");
    __builtin_amdgcn_sched_barrier(0);
    __builtin_amdgcn_s_setprio(1);
    #pragma unroll
    for (int m = 0; m < 4; ++m)
      #pragma unroll
      for (int n = 0; n < 4; ++n)
        acc[m][n] = __builtin_amdgcn_mfma_f32_16x16x32_bf16(aE[m], bb0[n], acc[m][n], 0, 0, 0);
    __builtin_amdgcn_s_setprio(0);
    __builtin_amdgcn_s_barrier();
    // ---- phase 1: read A[4..7][kk0], A[4..7][kk1], B[kk1]; MFMA (m4-7, kk0) ----
    #pragma unroll
    for (int m = 0; m < 4; ++m) { LDA_(aE[m], m+4, 0); LDA_(aL1[m], m+4, 1); }
    #pragma unroll
    for (int n = 0; n < 4; ++n) { LDB_(bb1[n], n, 1); }
    if (4*T+7 < 4*NT_TILES) STAGE_H(4*T+7);
    __builtin_amdgcn_s_barrier();
    asm volatile("s_waitcnt lgkmcnt(0)" ::: "memory");
    __builtin_amdgcn_sched_barrier(0);
    __builtin_amdgcn_s_setprio(1);
    #pragma unroll
    for (int m = 0; m < 4; ++m)
      #pragma unroll
      for (int n = 0; n < 4; ++n)
        acc[m+4][n] = __builtin_amdgcn_mfma_f32_16x16x32_bf16(aE[m], bb0[n], acc[m+4][n], 0, 0, 0);
    __builtin_amdgcn_s_setprio(0);
    __builtin_amdgcn_s_barrier();
    // ---- phase 2: (buf's A halves fully consumed) MFMA (m0-3, kk1) ----
    if (4*T+8 < 4*NT_TILES) STAGE_H(4*T+8);
    __builtin_amdgcn_s_barrier();
    __builtin_amdgcn_s_setprio(1);
    #pragma unroll
    for (int m = 0; m < 4; ++m)
      #pragma unroll
      for (int n = 0; n < 4; ++n)
        acc[m][n] = __builtin_amdgcn_mfma_f32_16x16x32_bf16(aL0[m], bb1[n], acc[m][n], 0, 0, 0);
    __builtin_amdgcn_s_setprio(0);
    __builtin_amdgcn_s_barrier();
    // ---- phase 3: MFMA (m4-7, kk1); tile-boundary wait ----
    if (4*T+9 < 4*NT_TILES) STAGE_H(4*T+9);
    __builtin_amdgcn_s_barrier();
    __builtin_amdgcn_s_setprio(1);
    #pragma unroll
    for (int m = 0; m < 4; ++m)
      #pragma unroll
      for (int n = 0; n < 4; ++n)
        acc[m+4][n] = __builtin_amdgcn_mfma_f32_16x16x32_bf16(aL1[m], bb1[n], acc[m+4][n], 0, 0, 0);
    __builtin_amdgcn_s_setprio(0);
    if (T < NT_TILES-2) { asm volatile("s_waitcnt vmcnt(4)" ::: "memory"); }
    else                { asm volatile("s_waitcnt vmcnt(0)" ::: "memory"); }   // R3-bug fix
    __builtin_amdgcn_s_barrier();
  }
}

// ---------------- kernel 1: QKV GEMM + RMSNorm + RoPE + scatter ----------------
__launch_bounds__(512)
__global__ void k_qkv(const unsigned short* __restrict__ A,    // x bf16 [65536][512], t = h*256+w
                      const unsigned short* __restrict__ B,    // w_qkv bf16 [1536][512]
                      const float* __restrict__ qnw, const float* __restrict__ knw,
                      const float2* __restrict__ rope,         // [256][32]
                      unsigned short* __restrict__ Qw,
                      unsigned short* __restrict__ Kw,
                      unsigned short* __restrict__ Vw) {
  __shared__ __align__(16) unsigned short L[2][2][2][128*64];  // 128 KiB
  // T1: 1536 = 8 XCD * 192; bn fastest within chunk -> A-tile L2 reuse
  int wg = (blockIdx.x & 7)*192 + (blockIdx.x >> 3);
  int bn = wg % 6, bm = wg / 6;
  f32x4 acc[8][4] = {};
  gemm256(A, B, bm*256, bn*256, L, acc);

  const int lane = threadIdx.x & 63, wid = threadIdx.x >> 6;
  const int wr = wid >> 2, wc = wid & 3;
  const int li = lane & 15, lg = lane >> 4;
  int d0 = bn*256 + wc*64;                 // 64-aligned => one (third, head) per wave
  int third = d0 >> 9;                     // 0=q 1=k 2=v
  int nhh = (d0 >> 6) & 7;
  int t0 = bm*256 + wr*128;
  int hpos = bm;                           // t>>8 == bm for the whole block

  if (third == 2) {
    #pragma unroll
    for (int m = 0; m < 8; ++m)
      #pragma unroll
      for (int n = 0; n < 4; ++n)
        #pragma unroll
        for (int r = 0; r < 4; ++r) {
          int t = t0 + m*16 + lg*4 + r;
          int wI = t & 255;
          int e = n*16 + li;
          Vw[((size_t)(wI*8 + nhh)*256 + hpos)*64 + e] = f2bf(acc[m][n][r]);
        }
  } else {
    const float* nw = (third == 0) ? qnw : knw;
    unsigned short* dst = (third == 0) ? Qw : Kw;
    const float qsc = (third == 0) ? 0.125f : 1.0f;   // fold hd^-0.5 into q
    float nwv[4]; float2 cs[4];
    #pragma unroll
    for (int n = 0; n < 4; ++n) {
      int e = n*16 + li;
      nwv[n] = nw[e];
      cs[n] = rope[hpos*32 + (e >> 1)];
    }
    bool odd = (li & 1) != 0;
    #pragma unroll
    for (int m = 0; m < 8; ++m) {
      float rsg[4];
      #pragma unroll
      for (int r = 0; r < 4; ++r) {
        float p = 0.f;
        #pragma unroll
        for (int n = 0; n < 4; ++n) p += acc[m][n][r]*acc[m][n][r];
        #pragma unroll
        for (int d = 1; d < 16; d <<= 1) p += __shfl_xor(p, d, 64);   // head-dim reduce (li group)
        rsg[r] = rsqrtf(p*(1.0f/64.0f) + 1e-6f);
      }
      #pragma unroll
      for (int n = 0; n < 4; ++n)
        #pragma unroll
        for (int r = 0; r < 4; ++r) {
          float v = acc[m][n][r] * rsg[r] * nwv[n];
          float pr = __shfl_xor(v, 1, 64);            // rope pair partner
          float res = odd ? (pr*cs[n].y + v*cs[n].x) : (v*cs[n].x - pr*cs[n].y);
          res *= qsc;
          int t = t0 + m*16 + lg*4 + r;
          int wI = t & 255;
          int e = n*16 + li;
          dst[((size_t)(wI*8 + nhh)*256 + hpos)*64 + e] = f2bf(res);
        }
    }
  }
}

// ---------------- kernel 1t: V [h][e] -> VT [e][h] per (w,head) ----------------
__global__ void k_vt(const unsigned short* __restrict__ V, unsigned short* __restrict__ VT) {
  int b = blockIdx.x;                      // (w*8+n), 2048
  const unsigned short* src = V + (size_t)b*SEQ*HD;
  unsigned short* dst = VT + (size_t)b*SEQ*HD;
  int l = threadIdx.x & 63, wid = threadIdx.x >> 6;
  int h0 = (l & 31) * 8;
  int ebase = wid*2 + (l >> 5);
  #pragma unroll
  for (int eo = 0; eo < 8; ++eo) {
    int e = eo*8 + ebase;
    u16x8 v;
    #pragma unroll
    for (int i = 0; i < 8; ++i) v[i] = src[(h0+i)*64 + e];   // L1-absorbed gathers
    *(u16x8*)&dst[e*256 + h0] = v;                           // coalesced 16B stores
  }
}

// ---------------- kernel 2: attention per (w, head) ----------------
__launch_bounds__(256, 2)
__global__ void k_attn(const unsigned short* __restrict__ Q,
                       const unsigned short* __restrict__ K,
                       const unsigned short* __restrict__ VT,
                       unsigned short* __restrict__ O) {
  __shared__ __align__(16) unsigned short P_lds[4][64*64];   // 8KB/wave, XOR-swizzled [q][key]
  int b = blockIdx.x;
  const unsigned short* Qb = Q  + (size_t)b*SEQ*HD;
  const unsigned short* Kb = K  + (size_t)b*SEQ*HD;
  const unsigned short* Vb = VT + (size_t)b*SEQ*HD;          // [e][h]
  const int lane = threadIdx.x & 63, wid = threadIdx.x >> 6;
  const int li = lane & 15, lg = lane >> 4;
  const int q0 = wid*64;
  char* Pw = (char*)&P_lds[wid][0];

  bf16x8 qf[4][2];                                           // Q resident in regs
  #pragma unroll
  for (int n = 0; n < 4; ++n)
    #pragma unroll
    for (int kk = 0; kk < 2; ++kk)
      qf[n][kk] = *(const bf16x8*)(Qb + (q0 + n*16 + li)*64 + kk*32 + lg*8);

  f32x4 oa[4][4] = {};
  float mrun[4], lrun[4];
  #pragma unroll
  for (int n = 0; n < 4; ++n) { mrun[n] = -1e30f; lrun[n] = 0.0f; }

  #pragma unroll 1
  for (int kb = 0; kb < 4; ++kb) {
    int key0 = kb*64;
    // S^T[key][q] = K @ Q^T  (reg-quad = 4 consecutive keys -> b64 pack into P[q][key])
    f32x4 s[4][4] = {};
    #pragma unroll
    for (int kk = 0; kk < 2; ++kk) {
      bf16x8 kf[4];
      #pragma unroll
      for (int m = 0; m < 4; ++m)
        kf[m] = *(const bf16x8*)(Kb + (key0 + m*16 + li)*64 + kk*32 + lg*8);
      __builtin_amdgcn_s_setprio(1);
      #pragma unroll
      for (int m = 0; m < 4; ++m)
        #pragma unroll
        for (int n = 0; n < 4; ++n)
          s[m][n] = __builtin_amdgcn_mfma_f32_16x16x32_bf16(kf[m], qf[n][kk], s[m][n], 0, 0, 0);
      __builtin_amdgcn_s_setprio(0);
    }
    // online softmax: per lane state for q = n*16+li (replicated across lg, kept consistent)
    float mx[4], al[4];
    #pragma unroll
    for (int n = 0; n < 4; ++n) {
      float v = -1e30f;
      #pragma unroll
      for (int m = 0; m < 4; ++m)
        #pragma unroll
        for (int r = 0; r < 4; ++r) v = fmaxf(v, s[m][n][r]);
      v = fmaxf(v, __shfl_xor(v, 16, 64));
      v = fmaxf(v, __shfl_xor(v, 32, 64));
      float mn = fmaxf(mrun[n], v);
      al[n] = __expf(mrun[n] - mn);
      mrun[n] = mn;
      mx[n] = mn;
    }
    float rs[4] = {0.f,0.f,0.f,0.f};
    #pragma unroll
    for (int m = 0; m < 4; ++m)
      #pragma unroll
      for (int n = 0; n < 4; ++n) {
        f32x4 sv = s[m][n];
        #pragma unroll
        for (int r = 0; r < 4; ++r) {
          float p = __expf(sv[r] - mx[n]);
          sv[r] = p; rs[n] += p;
        }
        unsigned lo = (unsigned)f2bf(sv[0]) | ((unsigned)f2bf(sv[1]) << 16);
        unsigned hi = (unsigned)f2bf(sv[2]) | ((unsigned)f2bf(sv[3]) << 16);
        uint2 pk; pk.x = lo; pk.y = hi;
        int q = n*16 + li;
        int off = (q*128 + (m*16 + lg*4)*2) ^ ((li & 7) << 4);   // XOR swizzle (T2)
        *(uint2*)(Pw + off) = pk;
      }
    #pragma unroll
    for (int n = 0; n < 4; ++n) {
      rs[n] += __shfl_xor(rs[n], 16, 64);
      rs[n] += __shfl_xor(rs[n], 32, 64);
      lrun[n] = lrun[n]*al[n] + rs[n];
    }
    // rescale O: broadcast alpha[q] from softmax layout to O layout
    #pragma unroll
    for (int mp = 0; mp < 4; ++mp)
      #pragma unroll
      for (int r = 0; r < 4; ++r) {
        float a = __shfl(al[mp], lg*4 + r, 64);
        #pragma unroll
        for (int np = 0; np < 4; ++np) oa[mp][np][r] *= a;
      }
    // PV: O[q][e] += P[q][key] @ V[key][e]  (A=P from swizzled LDS, B=VT from global)
    #pragma unroll
    for (int kk = 0; kk < 2; ++kk) {
      bf16x8 pf[4], vf[4];
      #pragma unroll
      for (int mp = 0; mp < 4; ++mp) {
        int q = mp*16 + li;
        int off = (q*128 + (kk*32 + lg*8)*2) ^ ((li & 7) << 4);
        pf[mp] = *(const bf16x8*)(Pw + off);
      }
      #pragma unroll
      for (int np = 0; np < 4; ++np)
        vf[np] = *(const bf16x8*)(Vb + (np*16 + li)*256 + key0 + kk*32 + lg*8);
      __builtin_amdgcn_s_setprio(1);
      #pragma unroll
      for (int mp = 0; mp < 4; ++mp)
        #pragma unroll
        for (int np = 0; np < 4; ++np)
          oa[mp][np] = __builtin_amdgcn_mfma_f32_16x16x32_bf16(pf[mp], vf[np], oa[mp][np], 0, 0, 0);
      __builtin_amdgcn_s_setprio(0);
    }
  }
  // finalize: divide by l, store O_ws rows t = h*256+w, cols head*64+e
  int wseq = b >> 3, whead = b & 7;
  #pragma unroll
  for (int mp = 0; mp < 4; ++mp)
    #pragma unroll
    for (int r = 0; r < 4; ++r) {
      float linv = 1.0f / __shfl(lrun[mp], lg*4 + r, 64);
      #pragma unroll
      for (int np = 0; np < 4; ++np) {
        int q = q0 + mp*16 + lg*4 + r;
        int e = np*16 + li;
        O[((size_t)q*WDIM + wseq)*CDIM + whead*HD + e] = f2bf(oa[mp][np][r] * linv);
      }
    }
}

// ---------------- kernel 3: out-proj GEMM + bias, fp32 out ----------------
__launch_bounds__(512)
__global__ void k_proj(const unsigned short* __restrict__ A,   // O bf16 [65536][512]
                       const unsigned short* __restrict__ B,   // w_proj bf16 [512][512]
                       const float* __restrict__ bias,
                       float* __restrict__ out) {
  __shared__ __align__(16) unsigned short L[2][2][2][128*64];  // 128 KiB
  // T1: 512 = 8 XCD * 64
  int wg = (blockIdx.x & 7)*64 + (blockIdx.x >> 3);
  int bn = wg & 1, bm = wg >> 1;
  f32x4 acc[8][4] = {};
  gemm256(A, B, bm*256, bn*256, L, acc);

  const int lane = threadIdx.x & 63, wid = threadIdx.x >> 6;
  const int wr = wid >> 2, wc = wid & 3;
  const int li = lane & 15, lg = lane >> 4;
  int d0 = bn*256 + wc*64;
  int t0 = bm*256 + wr*128;
  float bi[4];
  #pragma unroll
  for (int n = 0; n < 4; ++n) bi[n] = bias[d0 + n*16 + li];
  #pragma unroll
  for (int m = 0; m < 8; ++m)
    #pragma unroll
    for (int n = 0; n < 4; ++n)
      #pragma unroll
      for (int r = 0; r < 4; ++r)
        out[(size_t)(t0 + m*16 + lg*4 + r)*CDIM + d0 + n*16 + li] = acc[m][n][r] + bi[n];
}

extern "C" void kernel_launch(void* const* d_in, const int* in_sizes, int n_in,
                              void* d_out, int out_size, void* d_ws, size_t ws_size,
                              hipStream_t stream) {
  (void)in_sizes; (void)n_in; (void)out_size; (void)ws_size;
  const float* x     = (const float*)d_in[0];
  const float* wqkv  = (const float*)d_in[1];
  const float* qnw   = (const float*)d_in[2];
  const float* knw   = (const float*)d_in[3];
  const float* wproj = (const float*)d_in[4];
  const float* bproj = (const float*)d_in[5];
  float* out = (float*)d_out;
  char* ws = (char*)d_ws;

  const size_t SZ_X = (size_t)NTOK*CDIM*2;                     // 64 MiB of bf16
  unsigned short* xb  = (unsigned short*)(ws);
  unsigned short* wqb = (unsigned short*)(ws + SZ_X);
  unsigned short* wpb = (unsigned short*)(ws + SZ_X + 1572864);
  float2*         rp  = (float2*)       (ws + SZ_X + 1572864 + 524288);
  unsigned short* Qw  = (unsigned short*)(ws + SZ_X + 1572864 + 524288 + 65536);
  unsigned short* Kw  = (unsigned short*)((char*)Qw + SZ_X);
  unsigned short* Vw  = (unsigned short*)((char*)Kw + SZ_X);
  unsigned short* VTw = (unsigned short*)((char*)Vw + SZ_X);
  unsigned short* Ow  = xb;   // x is dead after k_qkv; reuse its slot for attention output

  k_convert<<<dim3(2048), dim3(256), 0, stream>>>(x, wqkv, wproj, xb, wqb, wpb);
  k_rope   <<<dim3(32),   dim3(256), 0, stream>>>(rp);
  k_qkv    <<<dim3(1536), dim3(512), 0, stream>>>(xb, wqb, qnw, knw, rp, Qw, Kw, Vw);
  k_vt     <<<dim3(2048), dim3(256), 0, stream>>>(Vw, VTw);
  k_attn   <<<dim3(2048), dim3(256), 0, stream>>>(Qw, Kw, VTw, Ow);
  k_proj   <<<dim3(512),  dim3(512), 0, stream>>>(Ow, wpb, bproj, out);
}